// Round 1
// baseline (60.559 us; speedup 1.0000x reference)
//
#include <hip/hip_runtime.h>

// out[b,k] = sum_n exp(-2*pi * ||dom_k - C[b,n]||^2)
//   exponent e = S1*(dom_k . c_n) - S2*||c_n||^2 - S2*||dom_k||^2, S2 = 2*pi/ln2
//   exp(-2*pi*theta) = exp2(e)  -> single v_exp_f32
// B=32, N=4096, K=2048. Compute-bound: 6 VALU-class ops per (b,k,n) pair.

#define NATOMS 4096
#define KTILE  128   // k values per block (2 threads per k, n-split by 2)

#if defined(__has_builtin)
#if __has_builtin(__builtin_amdgcn_exp2f)
#define HAVE_EXP2_BUILTIN 1
#endif
#endif

__device__ __forceinline__ float fast_exp2(float x) {
#ifdef HAVE_EXP2_BUILTIN
    return __builtin_amdgcn_exp2f(x);
#else
    float r;
    asm("v_exp_f32 %0, %1" : "=v"(r) : "v"(x));
    return r;
#endif
}

__global__ void theta_layer_kernel(const float* __restrict__ C,
                                   const float* __restrict__ dom,
                                   float* __restrict__ out, int K) {
    constexpr float S2 = 9.064720283654388f;   // 2*pi / ln(2)
    constexpr float S1 = 18.129440567308776f;  // 4*pi / ln(2)

    __shared__ float4 sC[NATOMS];  // {x, y, z, -S2*||c||^2} : 64 KB

    const int tid = threadIdx.x;
    const int b   = blockIdx.y;
    const int bx  = blockIdx.x;

    // ---- stage C[b] into LDS with precomputed norm term ----
    const float* Cb = C + (size_t)b * (NATOMS * 3);
    for (int n = tid; n < NATOMS; n += 256) {
        float x = Cb[3 * n + 0];
        float y = Cb[3 * n + 1];
        float z = Cb[3 * n + 2];
        sC[n] = make_float4(x, y, z, -S2 * (x * x + y * y + z * z));
    }

    // ---- per-thread k setup (2 threads per k: n-split halves) ----
    const int kk   = tid & (KTILE - 1);
    const int half = tid >> 7;               // 0 or 1
    const int k    = bx * KTILE + kk;
    const float dx = dom[3 * k + 0];
    const float dy = dom[3 * k + 1];
    const float dz = dom[3 * k + 2];
    const float xk = S1 * dx;
    const float yk = S1 * dy;
    const float zk = S1 * dz;
    const float dk = -S2 * (dx * dx + dy * dy + dz * dz);

    __syncthreads();

    // ---- inner loop: 3 FMA + 1 add + 1 v_exp_f32 + 1 acc add per pair ----
    float a0 = 0.f, a1 = 0.f, a2 = 0.f, a3 = 0.f;
    const float4* p = sC + half * (NATOMS / 2);
    for (int i = 0; i < NATOMS / 2; i += 4) {
        float4 c0 = p[i + 0];
        float4 c1 = p[i + 1];
        float4 c2 = p[i + 2];
        float4 c3 = p[i + 3];
        float t0 = fmaf(xk, c0.x, c0.w); t0 = fmaf(yk, c0.y, t0); t0 = fmaf(zk, c0.z, t0);
        a0 += fast_exp2(t0 + dk);
        float t1 = fmaf(xk, c1.x, c1.w); t1 = fmaf(yk, c1.y, t1); t1 = fmaf(zk, c1.z, t1);
        a1 += fast_exp2(t1 + dk);
        float t2 = fmaf(xk, c2.x, c2.w); t2 = fmaf(yk, c2.y, t2); t2 = fmaf(zk, c2.z, t2);
        a2 += fast_exp2(t2 + dk);
        float t3 = fmaf(xk, c3.x, c3.w); t3 = fmaf(yk, c3.y, t3); t3 = fmaf(zk, c3.z, t3);
        a3 += fast_exp2(t3 + dk);
    }
    float acc = (a0 + a1) + (a2 + a3);

    // ---- combine the two n-halves via LDS (reuse sC) ----
    __syncthreads();  // everyone done reading sC
    float* red = (float*)sC;
    red[tid] = acc;
    __syncthreads();
    if (tid < KTILE) {
        out[(size_t)b * K + bx * KTILE + tid] = red[tid] + red[tid + KTILE];
    }
}

extern "C" void kernel_launch(void* const* d_in, const int* in_sizes, int n_in,
                              void* d_out, int out_size, void* d_ws, size_t ws_size,
                              hipStream_t stream) {
    const float* C   = (const float*)d_in[0];
    const float* dom = (const float*)d_in[1];
    float* out       = (float*)d_out;
    const int B = in_sizes[0] / (NATOMS * 3);  // 32
    const int K = in_sizes[1] / 3;             // 2048
    dim3 grid(K / KTILE, B);
    theta_layer_kernel<<<grid, 256, 0, stream>>>(C, dom, out, K);
}

// Round 2
// 45.405 us; speedup vs baseline: 1.3337x; 1.3337x over previous
//
#include <hip/hip_runtime.h>

// out[b,k] = sum_n exp(-2*pi * ||dom_k - C[b,n]||^2)
//   exponent e = S1*(dom_k . c_n) - S2*||c_n||^2 - S2*||dom_k||^2, S2 = 2*pi/ln2
//   -> exp2(e) via v_exp_f32.
// B=32, N=4096, K=2048.
// Structure: 512-thread blocks, KTILE=128 k/block, each thread owns 2 k's
// (kk, kk+64) and 1/8 of the atoms (amortizes broadcast LDS reads over 2 k),
// packed-f32 math (v_pk_fma_f32) over atom pairs.

#define NATOMS 4096
#define NPAIRS (NATOMS / 2)
#define KTILE  128
#define BLOCK  512
#define NSPLIT 8                 // BLOCK / 64 lanes
#define PPT    (NPAIRS / NSPLIT) // atom-pairs per thread = 256

typedef float f2 __attribute__((ext_vector_type(2)));
typedef float f4 __attribute__((ext_vector_type(4)));

#if defined(__has_builtin)
#if __has_builtin(__builtin_amdgcn_exp2f)
#define HAVE_EXP2_BUILTIN 1
#endif
#endif

__device__ __forceinline__ float fast_exp2(float x) {
#ifdef HAVE_EXP2_BUILTIN
    return __builtin_amdgcn_exp2f(x);
#else
    float r;
    asm("v_exp_f32 %0, %1" : "=v"(r) : "v"(x));
    return r;
#endif
}

// Packed 2xf32 ops (full-rate on CDNA4, operands are even-aligned VGPR pairs)
__device__ __forceinline__ f2 pk_fma(f2 a, f2 b, f2 c) {
    f2 d;
    asm("v_pk_fma_f32 %0, %1, %2, %3" : "=v"(d) : "v"(a), "v"(b), "v"(c));
    return d;
}
__device__ __forceinline__ f2 pk_add(f2 a, f2 b) {
    f2 d;
    asm("v_pk_add_f32 %0, %1, %2" : "=v"(d) : "v"(a), "v"(b));
    return d;
}

__global__ __launch_bounds__(BLOCK, 4) void theta_layer_kernel(
        const float* __restrict__ C, const float* __restrict__ dom,
        float* __restrict__ out, int K) {
    constexpr float S2 = 9.064720283654388f;   // 2*pi / ln(2)
    constexpr float S1 = 18.129440567308776f;  // 4*pi / ln(2)

    // Atom-pair packed: sXY[j]={x0,x1,y0,y1}, sZW[j]={z0,z1,w0,w1}, w=-S2*||c||^2
    __shared__ f4 sXY[NPAIRS];   // 32 KB
    __shared__ f4 sZW[NPAIRS];   // 32 KB

    const int tid = threadIdx.x;
    const int b   = blockIdx.y;
    const int bx  = blockIdx.x;

    // ---- stage C[b] into LDS, pair-packed, with precomputed norm terms ----
    const float* Cb = C + (size_t)b * (NATOMS * 3);
    for (int j = tid; j < NPAIRS; j += BLOCK) {
        const float* p = Cb + 6 * j;
        float x0 = p[0], y0 = p[1], z0 = p[2];
        float x1 = p[3], y1 = p[4], z1 = p[5];
        f4 xy = {x0, x1, y0, y1};
        f4 zw = {z0, z1, -S2 * (x0 * x0 + y0 * y0 + z0 * z0),
                         -S2 * (x1 * x1 + y1 * y1 + z1 * z1)};
        sXY[j] = xy;
        sZW[j] = zw;
    }

    // ---- per-thread k setup: two k's per thread (kk and kk+64) ----
    const int kk   = tid & 63;
    const int part = tid >> 6;  // 0..7 : atom range split
    const int k0   = bx * KTILE + kk;
    const int k1   = k0 + 64;

    const float dx0 = dom[3 * k0], dy0 = dom[3 * k0 + 1], dz0 = dom[3 * k0 + 2];
    const float dx1 = dom[3 * k1], dy1 = dom[3 * k1 + 1], dz1 = dom[3 * k1 + 2];

    const f2 xk0 = {S1 * dx0, S1 * dx0};
    const f2 yk0 = {S1 * dy0, S1 * dy0};
    const f2 zk0 = {S1 * dz0, S1 * dz0};
    const f2 xk1 = {S1 * dx1, S1 * dx1};
    const f2 yk1 = {S1 * dy1, S1 * dy1};
    const f2 zk1 = {S1 * dz1, S1 * dz1};
    const float dkv0 = -S2 * (dx0 * dx0 + dy0 * dy0 + dz0 * dz0);
    const float dkv1 = -S2 * (dx1 * dx1 + dy1 * dy1 + dz1 * dz1);
    const f2 dk0 = {dkv0, dkv0};
    const f2 dk1 = {dkv1, dkv1};

    __syncthreads();

    // ---- main loop: per iter = 2 atoms x 2 k = 4 exps, 2 ds_read_b128 ----
    float a00 = 0.f, a01 = 0.f, a10 = 0.f, a11 = 0.f;
    const int j0 = part * PPT;
    #pragma unroll 2
    for (int j = j0; j < j0 + PPT; ++j) {
        f4 xy = sXY[j];
        f4 zw = sZW[j];
        f2 x01 = __builtin_shufflevector(xy, xy, 0, 1);
        f2 y01 = __builtin_shufflevector(xy, xy, 2, 3);
        f2 z01 = __builtin_shufflevector(zw, zw, 0, 1);
        f2 w01 = __builtin_shufflevector(zw, zw, 2, 3);

        f2 t0 = pk_fma(z01, zk0, w01);
        t0 = pk_fma(y01, yk0, t0);
        t0 = pk_fma(x01, xk0, t0);
        t0 = pk_add(t0, dk0);
        a00 += fast_exp2(t0.x);
        a01 += fast_exp2(t0.y);

        f2 t1 = pk_fma(z01, zk1, w01);
        t1 = pk_fma(y01, yk1, t1);
        t1 = pk_fma(x01, xk1, t1);
        t1 = pk_add(t1, dk1);
        a10 += fast_exp2(t1.x);
        a11 += fast_exp2(t1.y);
    }
    const float r0 = a00 + a01;
    const float r1 = a10 + a11;

    // ---- reduce the 8 n-parts per k via LDS (reuse sXY) ----
    __syncthreads();  // all reads of sXY/sZW done
    float* red = (float*)sXY;  // [NSPLIT][KTILE]
    red[part * KTILE + kk]      = r0;
    red[part * KTILE + kk + 64] = r1;
    __syncthreads();
    if (tid < KTILE) {
        float s = 0.f;
        #pragma unroll
        for (int p = 0; p < NSPLIT; ++p) s += red[p * KTILE + tid];
        out[(size_t)b * K + bx * KTILE + tid] = s;
    }
}

extern "C" void kernel_launch(void* const* d_in, const int* in_sizes, int n_in,
                              void* d_out, int out_size, void* d_ws, size_t ws_size,
                              hipStream_t stream) {
    const float* C   = (const float*)d_in[0];
    const float* dom = (const float*)d_in[1];
    float* out       = (float*)d_out;
    const int B = in_sizes[0] / (NATOMS * 3);  // 32
    const int K = in_sizes[1] / 3;             // 2048
    dim3 grid(K / KTILE, B);
    theta_layer_kernel<<<grid, BLOCK, 0, stream>>>(C, dom, out, K);
}